// Round 11
// baseline (330.751 us; speedup 1.0000x reference)
//
#include <hip/hip_runtime.h>

typedef float  f32x4  __attribute__((ext_vector_type(4)));
typedef __bf16 bf16x8 __attribute__((ext_vector_type(8)));

#define N_NODES 16384
#define K_DIM   16384
#define H1_DIM  50
#define H1_PAD  64
#define CAP     160
#define OUT_OFF (N_NODES * 7)

typedef const __attribute__((address_space(1))) unsigned int* gas_ptr;
typedef __attribute__((address_space(3))) unsigned int* las_ptr;
__device__ __forceinline__ void gload_lds16(const void* g, void* l) {
  __builtin_amdgcn_global_load_lds((gas_ptr)g, (las_ptr)l, 16, 0, 0);
}

// ---- fused: W1->WT transpose (blocks 0..255) + bucket fill (blocks 256+), single edge pass ----
__global__ __launch_bounds__(256) void k_pre(const float* __restrict__ W1, __bf16* __restrict__ WT,
                                             const int* __restrict__ src, const int* __restrict__ dst,
                                             int E, int* cnt, int* bucket) {
  int t = threadIdx.x;
  if (blockIdx.x < 256) {
    __shared__ __bf16 lds[64][80];
    int k0 = blockIdx.x * 64;
    int rq = t >> 6, c = t & 63;
    for (int r = 0; r < 16; ++r) {
      int row = rq * 16 + r;
      __bf16 v = (__bf16)0.f;
      if (c < H1_DIM) v = (__bf16)W1[(size_t)(k0 + row) * H1_DIM + c];
      lds[c][row] = v;
    }
    __syncthreads();
    int cw = t >> 2, kq = (t & 3) * 16;
    __bf16* dp = WT + (size_t)cw * K_DIM + k0 + kq;
    *(bf16x8*)dp       = *(const bf16x8*)&lds[cw][kq];
    *((bf16x8*)dp + 1) = *(const bf16x8*)&lds[cw][kq + 8];
  } else {
    int e = (blockIdx.x - 256) * 256 + t;
    if (e < E) {
      int d = dst[e];
      int pos = atomicAdd(&cnt[d], 1);
      if (pos < CAP) bucket[(size_t)d * CAP + pos] = src[e];
    }
  }
}

// ---------------- GEMM1: xw[r][c] += dinv[r]*(x @ W1)[r][c]  (BARRIER-FREE wave-private LDS) ----
// Each wave owns As[w] (its 16 rows x 64k f32, 4 KB) and Bs[w] (full 64x64k bf16, 8 KB).
// Loop: 12 wave-local gload_lds -> s_waitcnt vmcnt(0) -> compute. NO __syncthreads anywhere:
// 12 independent wave-pipelines/CU de-phase naturally, covering each other's stage latency
// (the R8-R10 block-synchronous structure kept all drain windows wall-clock aligned).
// Swizzle (both sides): A 16B-chunk at chunk ^ (row_local&15); B chunk at chunk ^ (col&7).
__global__ __launch_bounds__(256) void k_gemm1(const float* __restrict__ x,
                                               const __bf16* __restrict__ WT,
                                               const int* __restrict__ cnt,
                                               float* __restrict__ xw) {
  __shared__ float  As[4][16 * 64];   // 16 KB total, wave-private quarters
  __shared__ __bf16 Bs[4][64 * 64];   // 32 KB total, wave-private quarters
  int tid = threadIdx.x;
  int w = tid >> 6, l = tid & 63;
  int l15 = l & 15, l7 = l & 7, g2 = l >> 4;
  int row0 = blockIdx.x * 64;
  int kbase = blockIdx.y * 4096;

  int a_rl = l >> 4;                  // 0..3: sub-row within a stage call
  int b_cl = l >> 3;                  // 0..7: base col within a stage call

  // stage sources (pre-swizzled). A call c covers row_local = c*4 + a_rl.
  const float* ga[4];
#pragma unroll
  for (int c = 0; c < 4; ++c) {
    int rl = (c << 2) | a_rl;
    ga[c] = x + (size_t)(row0 + w * 16 + rl) * K_DIM + kbase + ((l15 ^ rl) << 2);
  }
  // B call c covers col = c*8 + b_cl; chunk key = l7 ^ (col&7) = l7 ^ b_cl (c-invariant).
  const __bf16* gb = WT + (size_t)b_cl * K_DIM + kbase + ((l7 ^ b_cl) << 3);

  float*  asw = &As[w][0];
  __bf16* bsw = &Bs[w][0];

  f32x4 acc0 = {0,0,0,0}, acc1 = {0,0,0,0}, acc2 = {0,0,0,0}, acc3 = {0,0,0,0};

  for (int ks = 0; ks < 64; ++ks) {
    int kk = ks * 64;
    // ---- wave-local stage (12 x 1KB); dest linear, source pre-swizzled
#pragma unroll
    for (int c = 0; c < 4; ++c) gload_lds16(ga[c] + kk, asw + c * 256);
#pragma unroll
    for (int c = 0; c < 8; ++c) gload_lds16(gb + (size_t)c * 8 * K_DIM + kk, bsw + c * 512);
    asm volatile("s_waitcnt vmcnt(0)" ::: "memory");   // wave-local: only this wave's 12 loads
    __builtin_amdgcn_sched_barrier(0);
    // ---- compute: 2 K-subtiles of 32 (reads own LDS quarter only)
#pragma unroll
    for (int s = 0; s < 2; ++s) {
      int c0 = s * 8 + g2 * 2;
      f32x4 a0 = *(const f32x4*)&asw[l15 * 64 + (((c0    ) ^ l15) << 2)];
      f32x4 a1 = *(const f32x4*)&asw[l15 * 64 + (((c0 + 1) ^ l15) << 2)];
      bf16x8 af;
      af[0] = (__bf16)a0[0]; af[1] = (__bf16)a0[1]; af[2] = (__bf16)a0[2]; af[3] = (__bf16)a0[3];
      af[4] = (__bf16)a1[0]; af[5] = (__bf16)a1[1]; af[6] = (__bf16)a1[2]; af[7] = (__bf16)a1[3];
      int cb = (s * 4 + g2) ^ l7;   // swizzled B chunk
      bf16x8 b0 = *(const bf16x8*)&bsw[(     l15) * 64 + (cb << 3)];
      bf16x8 b1 = *(const bf16x8*)&bsw[(16 + l15) * 64 + (cb << 3)];
      bf16x8 b2 = *(const bf16x8*)&bsw[(32 + l15) * 64 + (cb << 3)];
      bf16x8 b3 = *(const bf16x8*)&bsw[(48 + l15) * 64 + (cb << 3)];
      acc0 = __builtin_amdgcn_mfma_f32_16x16x32_bf16(af, b0, acc0, 0, 0, 0);
      acc1 = __builtin_amdgcn_mfma_f32_16x16x32_bf16(af, b1, acc1, 0, 0, 0);
      acc2 = __builtin_amdgcn_mfma_f32_16x16x32_bf16(af, b2, acc2, 0, 0, 0);
      acc3 = __builtin_amdgcn_mfma_f32_16x16x32_bf16(af, b3, acc3, 0, 0, 0);
    }
    // no barrier: iter t's ds_reads complete (lgkmcnt before their MFMAs) before
    // iter t+1's gload data can land (vmem round-trip >> LDS latency)
  }

  // C layout: col = lane&15, row = (lane>>4)*4 + reg; scale by dinv[row] = rsqrt(cnt+1) here
  int crow = row0 + w * 16 + g2 * 4;
#pragma unroll
  for (int j = 0; j < 4; ++j) {
    float dv = rsqrtf((float)(cnt[crow + j] + 1));
    size_t rb = (size_t)(crow + j) * H1_PAD + l15;
    atomicAdd(&xw[rb],      acc0[j] * dv);
    atomicAdd(&xw[rb + 16], acc1[j] * dv);
    atomicAdd(&xw[rb + 32], acc2[j] * dv);
    atomicAdd(&xw[rb + 48], acc3[j] * dv);
  }
}

// ---- layer-1 aggregation (xw rows pre-scaled by dinv[src]) FUSED with layer-2 transform ----
__global__ __launch_bounds__(256) void k_agg1(const float* __restrict__ xw,
                                              const int* __restrict__ cnt,
                                              const int* __restrict__ bucket,
                                              const float* __restrict__ b1,
                                              const float* __restrict__ W2,
                                              float* __restrict__ xw2s) {
  int tid = threadIdx.x;
  int nid = blockIdx.x * 4 + (tid >> 6);
  int j = tid & 63;
  float acc = xw[(size_t)nid * H1_PAD + j];  // self term (pre-scaled)
  int cn0 = cnt[nid];
  int cn = cn0 > CAP ? CAP : cn0;
  const int* bp = bucket + (size_t)nid * CAP;
  int p = 0;
  for (; p + 3 < cn; p += 4) {
    int s0 = bp[p], s1 = bp[p + 1], s2 = bp[p + 2], s3 = bp[p + 3];
    acc += xw[(size_t)s0 * H1_PAD + j];
    acc += xw[(size_t)s1 * H1_PAD + j];
    acc += xw[(size_t)s2 * H1_PAD + j];
    acc += xw[(size_t)s3 * H1_PAD + j];
  }
  for (; p < cn; ++p) acc += xw[(size_t)bp[p] * H1_PAD + j];

  float dv = rsqrtf((float)(cn0 + 1));
  float bj = (j < H1_DIM) ? b1[j] : 0.f;
  float h = tanhf(dv * acc + bj);
  float w0 = (j < H1_DIM) ? W2[j * 2]     : 0.f;
  float w1 = (j < H1_DIM) ? W2[j * 2 + 1] : 0.f;
  float a0 = h * w0, a1 = h * w1;
#pragma unroll
  for (int off = 32; off >= 1; off >>= 1) {
    a0 += __shfl_xor(a0, off);
    a1 += __shfl_xor(a1, off);
  }
  if (j == 0) {
    xw2s[nid * 2]     = a0 * dv;
    xw2s[nid * 2 + 1] = a1 * dv;
  }
}

// ---------------- layer-2 aggregation + tanh + classifier ----------------
__global__ __launch_bounds__(256) void k_final(const float* __restrict__ xw2s,
                                               const int* __restrict__ cnt,
                                               const int* __restrict__ bucket,
                                               const float* __restrict__ b2,
                                               const float* __restrict__ Wc,
                                               const float* __restrict__ bc,
                                               float* __restrict__ dout) {
  int tid = threadIdx.x;
  int g = tid >> 4, r = tid & 15;
  int nid = blockIdx.x * 16 + g;
  int cn0 = cnt[nid];
  int cn = cn0 > CAP ? CAP : cn0;
  const int* bp = bucket + (size_t)nid * CAP;
  float a0 = 0.f, a1 = 0.f;
  for (int p = r; p < cn; p += 16) {
    int sc = bp[p];
    a0 += xw2s[sc * 2];
    a1 += xw2s[sc * 2 + 1];
  }
#pragma unroll
  for (int off = 8; off >= 1; off >>= 1) {
    a0 += __shfl_xor(a0, off, 16);
    a1 += __shfl_xor(a1, off, 16);
  }
  if (r == 0) {
    a0 += xw2s[nid * 2];
    a1 += xw2s[nid * 2 + 1];
    float dv = rsqrtf((float)(cn0 + 1));
    float h0  = tanhf(dv * a0 + b2[0]);
    float h1v = tanhf(dv * a1 + b2[1]);
#pragma unroll
    for (int j = 0; j < 7; ++j)
      dout[nid * 7 + j] = h0 * Wc[j] + h1v * Wc[7 + j] + bc[j];
    dout[OUT_OFF + nid * 2]     = h0;
    dout[OUT_OFF + nid * 2 + 1] = h1v;
  }
}

extern "C" void kernel_launch(void* const* d_in, const int* in_sizes, int n_in,
                              void* d_out, int out_size, void* d_ws, size_t ws_size,
                              hipStream_t stream) {
  const float* x  = (const float*)d_in[0];
  const int*   ei = (const int*)d_in[1];
  const float* W1 = (const float*)d_in[2];
  const float* b1 = (const float*)d_in[3];
  const float* W2 = (const float*)d_in[4];
  const float* b2 = (const float*)d_in[5];
  const float* Wc = (const float*)d_in[6];
  const float* bc = (const float*)d_in[7];
  float* dout = (float*)d_out;
  const int E = in_sizes[1] / 2;
  const int* esrc = ei;
  const int* edst = ei + E;

  char* ws = (char*)d_ws;
  float*  xw      = (float*)(ws + 0x0000000);   // 4 MiB  [16384][64]
  __bf16* WT      = (__bf16*)(ws + 0x0400000);  // 2 MiB  [64][16384]
  int*    cnt     = (int*)(ws + 0x0600000);     // 64 KiB
  int*    bucket  = (int*)(ws + 0x0620000);     // 10 MiB [16384][160]
  float*  xw2s    = (float*)(ws + 0x1100000);   // 128 KiB

  hipMemsetAsync(cnt, 0, N_NODES * sizeof(int), stream);
  hipMemsetAsync(xw, 0, N_NODES * H1_PAD * sizeof(float), stream);
  k_pre<<<256 + (E + 255) / 256, 256, 0, stream>>>(W1, WT, esrc, edst, E, cnt, bucket);
  k_gemm1<<<dim3(256, 4), 256, 0, stream>>>(x, WT, cnt, xw);
  k_agg1<<<N_NODES / 4, 256, 0, stream>>>(xw, cnt, bucket, b1, W2, xw2s);
  k_final<<<N_NODES / 16, 256, 0, stream>>>(xw2s, cnt, bucket, b2, Wc, bc, dout);
}

// Round 12
// 294.892 us; speedup vs baseline: 1.1216x; 1.1216x over previous
//
#include <hip/hip_runtime.h>

typedef float  f32x4  __attribute__((ext_vector_type(4)));
typedef __bf16 bf16x8 __attribute__((ext_vector_type(8)));

#define N_NODES 16384
#define K_DIM   16384
#define H1_DIM  50
#define H1_PAD  64
#define CAP     160
#define OUT_OFF (N_NODES * 7)

typedef const __attribute__((address_space(1))) unsigned int* gas_ptr;
typedef __attribute__((address_space(3))) unsigned int* las_ptr;
__device__ __forceinline__ void gload_lds16(const void* g, void* l) {
  __builtin_amdgcn_global_load_lds((gas_ptr)g, (las_ptr)l, 16, 0, 0);
}

// ---- k_init: blocks 0..255 W1->WT transpose; 256..1279 zero xw; 1280..1343 zero cnt ----
__global__ __launch_bounds__(256) void k_init(const float* __restrict__ W1, __bf16* __restrict__ WT,
                                              float* __restrict__ xw, int* __restrict__ cnt) {
  int t = threadIdx.x, b = blockIdx.x;
  if (b < 256) {
    __shared__ __bf16 lds[64][80];
    int k0 = b * 64;
    int rq = t >> 6, c = t & 63;
    for (int r = 0; r < 16; ++r) {
      int row = rq * 16 + r;
      __bf16 v = (__bf16)0.f;
      if (c < H1_DIM) v = (__bf16)W1[(size_t)(k0 + row) * H1_DIM + c];
      lds[c][row] = v;
    }
    __syncthreads();
    int cw = t >> 2, kq = (t & 3) * 16;
    __bf16* dp = WT + (size_t)cw * K_DIM + k0 + kq;
    *(bf16x8*)dp       = *(const bf16x8*)&lds[cw][kq];
    *((bf16x8*)dp + 1) = *(const bf16x8*)&lds[cw][kq + 8];
  } else if (b < 1280) {
    int i = (b - 256) * 1024 + t * 4;
    *(f32x4*)&xw[i] = (f32x4){0.f, 0.f, 0.f, 0.f};
  } else {
    cnt[(b - 1280) * 256 + t] = 0;
  }
}

// ---- GEMM1 (blocks 0..1023): xw[r][c] += (x @ W1)[r][c]  (R10 structure, unscaled epilogue)
//      + bucket-fill (blocks 1024+): backfills the 2 spare block slots/CU during the GEMM.
// As[64r][64k] f32 + Bs[64c][64k] bf16 = 24 KB; GEMM = 4 blocks/CU; K-phase stagger kept.
// Swizzle (both sides): A 16B-chunk c at c ^ (row&15); B chunk at c ^ (col&7).
__global__ __launch_bounds__(256) void k_gemm1(const float* __restrict__ x,
                                               const __bf16* __restrict__ WT,
                                               const int* __restrict__ src,
                                               const int* __restrict__ dst, int E,
                                               int* cnt, int* bucket,
                                               float* __restrict__ xw) {
  __shared__ float  As[64 * 64];
  __shared__ __bf16 Bs[64 * 64];
  int tid = threadIdx.x;
  int gid = blockIdx.x;
  if (gid >= 1024) {          // ---- bucket-fill branch (no LDS touched)
    int e = (gid - 1024) * 256 + tid;
    if (e < E) {
      int d = dst[e];
      int pos = atomicAdd(&cnt[d], 1);
      if (pos < CAP) bucket[(size_t)d * CAP + pos] = src[e];
    }
    return;
  }
  int bx = gid >> 2, by = gid & 3;
  int w = tid >> 6, l = tid & 63;
  int l15 = l & 15, l7 = l & 7, g2 = l >> 4;
  int row0 = bx * 64;
  int kbase = by * 4096;

  int a_row = w * 4 + (l >> 4);   // + c*16  (stage row)
  int b_col = w * 8 + (l >> 3);   // + c*32  (stage col)
  int m_row = w * 16 + l15;       // compute: A row within tile

  int phase = ((bx + (bx >> 3) + by) & 3) << 4;

  f32x4 acc0 = {0,0,0,0}, acc1 = {0,0,0,0}, acc2 = {0,0,0,0}, acc3 = {0,0,0,0};

  for (int it = 0; it < 64; ++it) {
    int ks = (it + phase) & 63;
    int kk = kbase + ks * 64;
#pragma unroll
    for (int c = 0; c < 4; ++c) {
      int r = c * 16 + a_row;
      const float* gp = x + (size_t)(row0 + r) * K_DIM + kk + ((l15 ^ (r & 15)) << 2);
      gload_lds16(gp, &As[c * 1024 + w * 256]);
    }
#pragma unroll
    for (int c = 0; c < 2; ++c) {
      int col = c * 32 + b_col;
      const __bf16* gp = WT + (size_t)col * K_DIM + kk + ((l7 ^ (col & 7)) << 3);
      gload_lds16(gp, &Bs[c * 2048 + w * 512]);
    }
    __syncthreads();
#pragma unroll
    for (int s = 0; s < 2; ++s) {
      int c0 = s * 8 + g2 * 2;
      f32x4 a0 = *(const f32x4*)&As[m_row * 64 + (((c0    ) ^ l15) << 2)];
      f32x4 a1 = *(const f32x4*)&As[m_row * 64 + (((c0 + 1) ^ l15) << 2)];
      bf16x8 af;
      af[0] = (__bf16)a0[0]; af[1] = (__bf16)a0[1]; af[2] = (__bf16)a0[2]; af[3] = (__bf16)a0[3];
      af[4] = (__bf16)a1[0]; af[5] = (__bf16)a1[1]; af[6] = (__bf16)a1[2]; af[7] = (__bf16)a1[3];
      int cb = (s * 4 + g2) ^ l7;   // swizzled B chunk
      bf16x8 b0 = *(const bf16x8*)&Bs[(     l15) * 64 + (cb << 3)];
      bf16x8 b1 = *(const bf16x8*)&Bs[(16 + l15) * 64 + (cb << 3)];
      bf16x8 b2 = *(const bf16x8*)&Bs[(32 + l15) * 64 + (cb << 3)];
      bf16x8 b3 = *(const bf16x8*)&Bs[(48 + l15) * 64 + (cb << 3)];
      acc0 = __builtin_amdgcn_mfma_f32_16x16x32_bf16(af, b0, acc0, 0, 0, 0);
      acc1 = __builtin_amdgcn_mfma_f32_16x16x32_bf16(af, b1, acc1, 0, 0, 0);
      acc2 = __builtin_amdgcn_mfma_f32_16x16x32_bf16(af, b2, acc2, 0, 0, 0);
      acc3 = __builtin_amdgcn_mfma_f32_16x16x32_bf16(af, b3, acc3, 0, 0, 0);
    }
    __syncthreads();
  }

  // C layout: col = lane&15, row = (lane>>4)*4 + reg; UNSCALED (dinv applied in k_agg1)
  int crow = row0 + w * 16 + g2 * 4;
#pragma unroll
  for (int j = 0; j < 4; ++j) {
    size_t rb = (size_t)(crow + j) * H1_PAD + l15;
    atomicAdd(&xw[rb],      acc0[j]);
    atomicAdd(&xw[rb + 16], acc1[j]);
    atomicAdd(&xw[rb + 32], acc2[j]);
    atomicAdd(&xw[rb + 48], acc3[j]);
  }
}

// ---- layer-1 aggregation (dinv[src] = rsqrt(cnt+1) applied per edge) FUSED with layer-2 transform ----
__global__ __launch_bounds__(256) void k_agg1(const float* __restrict__ xw,
                                              const int* __restrict__ cnt,
                                              const int* __restrict__ bucket,
                                              const float* __restrict__ b1,
                                              const float* __restrict__ W2,
                                              float* __restrict__ xw2s) {
  int tid = threadIdx.x;
  int nid = blockIdx.x * 4 + (tid >> 6);
  int j = tid & 63;
  int cn0 = cnt[nid];
  int cn = cn0 > CAP ? CAP : cn0;
  float dv = rsqrtf((float)(cn0 + 1));
  float acc = dv * xw[(size_t)nid * H1_PAD + j];  // self term: dinv_i * xw_i
  const int* bp = bucket + (size_t)nid * CAP;
  int p = 0;
  for (; p + 3 < cn; p += 4) {
    int s0 = bp[p], s1 = bp[p + 1], s2 = bp[p + 2], s3 = bp[p + 3];
    float d0 = rsqrtf((float)(cnt[s0] + 1));
    float d1 = rsqrtf((float)(cnt[s1] + 1));
    float d2 = rsqrtf((float)(cnt[s2] + 1));
    float d3 = rsqrtf((float)(cnt[s3] + 1));
    acc += d0 * xw[(size_t)s0 * H1_PAD + j];
    acc += d1 * xw[(size_t)s1 * H1_PAD + j];
    acc += d2 * xw[(size_t)s2 * H1_PAD + j];
    acc += d3 * xw[(size_t)s3 * H1_PAD + j];
  }
  for (; p < cn; ++p) {
    int sc = bp[p];
    acc += rsqrtf((float)(cnt[sc] + 1)) * xw[(size_t)sc * H1_PAD + j];
  }

  float bj = (j < H1_DIM) ? b1[j] : 0.f;
  float h = tanhf(dv * acc + bj);
  float w0 = (j < H1_DIM) ? W2[j * 2]     : 0.f;
  float w1 = (j < H1_DIM) ? W2[j * 2 + 1] : 0.f;
  float a0 = h * w0, a1 = h * w1;
#pragma unroll
  for (int off = 32; off >= 1; off >>= 1) {
    a0 += __shfl_xor(a0, off);
    a1 += __shfl_xor(a1, off);
  }
  if (j == 0) {
    xw2s[nid * 2]     = a0 * dv;
    xw2s[nid * 2 + 1] = a1 * dv;
  }
}

// ---------------- layer-2 aggregation + tanh + classifier ----------------
__global__ __launch_bounds__(256) void k_final(const float* __restrict__ xw2s,
                                               const int* __restrict__ cnt,
                                               const int* __restrict__ bucket,
                                               const float* __restrict__ b2,
                                               const float* __restrict__ Wc,
                                               const float* __restrict__ bc,
                                               float* __restrict__ dout) {
  int tid = threadIdx.x;
  int g = tid >> 4, r = tid & 15;
  int nid = blockIdx.x * 16 + g;
  int cn0 = cnt[nid];
  int cn = cn0 > CAP ? CAP : cn0;
  const int* bp = bucket + (size_t)nid * CAP;
  float a0 = 0.f, a1 = 0.f;
  for (int p = r; p < cn; p += 16) {
    int sc = bp[p];
    a0 += xw2s[sc * 2];
    a1 += xw2s[sc * 2 + 1];
  }
#pragma unroll
  for (int off = 8; off >= 1; off >>= 1) {
    a0 += __shfl_xor(a0, off, 16);
    a1 += __shfl_xor(a1, off, 16);
  }
  if (r == 0) {
    a0 += xw2s[nid * 2];
    a1 += xw2s[nid * 2 + 1];
    float dv = rsqrtf((float)(cn0 + 1));
    float h0  = tanhf(dv * a0 + b2[0]);
    float h1v = tanhf(dv * a1 + b2[1]);
#pragma unroll
    for (int j = 0; j < 7; ++j)
      dout[nid * 7 + j] = h0 * Wc[j] + h1v * Wc[7 + j] + bc[j];
    dout[OUT_OFF + nid * 2]     = h0;
    dout[OUT_OFF + nid * 2 + 1] = h1v;
  }
}

extern "C" void kernel_launch(void* const* d_in, const int* in_sizes, int n_in,
                              void* d_out, int out_size, void* d_ws, size_t ws_size,
                              hipStream_t stream) {
  const float* x  = (const float*)d_in[0];
  const int*   ei = (const int*)d_in[1];
  const float* W1 = (const float*)d_in[2];
  const float* b1 = (const float*)d_in[3];
  const float* W2 = (const float*)d_in[4];
  const float* b2 = (const float*)d_in[5];
  const float* Wc = (const float*)d_in[6];
  const float* bc = (const float*)d_in[7];
  float* dout = (float*)d_out;
  const int E = in_sizes[1] / 2;
  const int* esrc = ei;
  const int* edst = ei + E;

  char* ws = (char*)d_ws;
  float*  xw      = (float*)(ws + 0x0000000);   // 4 MiB  [16384][64]
  __bf16* WT      = (__bf16*)(ws + 0x0400000);  // 2 MiB  [64][16384]
  int*    cnt     = (int*)(ws + 0x0600000);     // 64 KiB
  int*    bucket  = (int*)(ws + 0x0620000);     // 10 MiB [16384][160]
  float*  xw2s    = (float*)(ws + 0x1100000);   // 128 KiB

  k_init<<<1344, 256, 0, stream>>>(W1, WT, xw, cnt);
  k_gemm1<<<1024 + (E + 255) / 256, 256, 0, stream>>>(x, WT, esrc, edst, E, cnt, bucket, xw);
  k_agg1<<<N_NODES / 4, 256, 0, stream>>>(xw, cnt, bucket, b1, W2, xw2s);
  k_final<<<N_NODES / 16, 256, 0, stream>>>(xw2s, cnt, bucket, b2, Wc, bc, dout);
}

// Round 13
// 268.660 us; speedup vs baseline: 1.2311x; 1.0976x over previous
//
#include <hip/hip_runtime.h>

typedef float  f32x4  __attribute__((ext_vector_type(4)));
typedef int    i32x4  __attribute__((ext_vector_type(4)));
typedef __bf16 bf16x8 __attribute__((ext_vector_type(8)));

#define N_NODES 16384
#define K_DIM   16384
#define H1_DIM  50
#define H1_PAD  64
#define CAP     160
#define OUT_OFF (N_NODES * 7)

typedef const __attribute__((address_space(1))) unsigned int* gas_ptr;
typedef __attribute__((address_space(3))) unsigned int* las_ptr;
__device__ __forceinline__ void gload_lds16(const void* g, void* l) {
  __builtin_amdgcn_global_load_lds((gas_ptr)g, (las_ptr)l, 16, 0, 0);
}

// ---- k_init: blocks 0..255 W1->WT transpose; 256..1279 zero xw; 1280..1343 zero cnt ----
__global__ __launch_bounds__(256) void k_init(const float* __restrict__ W1, __bf16* __restrict__ WT,
                                              float* __restrict__ xw, int* __restrict__ cnt) {
  int t = threadIdx.x, b = blockIdx.x;
  if (b < 256) {
    __shared__ __bf16 lds[64][80];
    int k0 = b * 64;
    int rq = t >> 6, c = t & 63;
    for (int r = 0; r < 16; ++r) {
      int row = rq * 16 + r;
      __bf16 v = (__bf16)0.f;
      if (c < H1_DIM) v = (__bf16)W1[(size_t)(k0 + row) * H1_DIM + c];
      lds[c][row] = v;
    }
    __syncthreads();
    int cw = t >> 2, kq = (t & 3) * 16;
    __bf16* dp = WT + (size_t)cw * K_DIM + k0 + kq;
    *(bf16x8*)dp       = *(const bf16x8*)&lds[cw][kq];
    *((bf16x8*)dp + 1) = *(const bf16x8*)&lds[cw][kq + 8];
  } else if (b < 1280) {
    int i = (b - 256) * 1024 + t * 4;
    *(f32x4*)&xw[i] = (f32x4){0.f, 0.f, 0.f, 0.f};
  } else {
    cnt[(b - 1280) * 256 + t] = 0;
  }
}

// ---------------- bucket fill (single edge pass; cnt pre-zeroed by k_init) ----------------
__global__ __launch_bounds__(256) void k_fill(const int* __restrict__ src, const int* __restrict__ dst,
                                              int E, int* cnt, int* bucket) {
  int e = blockIdx.x * 256 + threadIdx.x;
  if (e < E) {
    int d = dst[e];
    int pos = atomicAdd(&cnt[d], 1);
    if (pos < CAP) bucket[(size_t)d * CAP + pos] = src[e];
  }
}

// ---------------- GEMM1: xw[r][c] += dinv[r]*(x @ W1)[r][c]  (R10 champion, unchanged) ---------
// As[64r][64k] f32 (16 KB) + Bs[64c][64k] bf16 (8 KB) = 24 KB -> 4 blocks/CU at grid 1024.
// K-phase stagger de-correlates co-resident blocks' stage addresses.
// Swizzle (both sides): A 16B-chunk c stored at c ^ (row&15); B chunk at c ^ (col&7).
__global__ __launch_bounds__(256) void k_gemm1(const float* __restrict__ x,
                                               const __bf16* __restrict__ WT,
                                               const int* __restrict__ cnt,
                                               float* __restrict__ xw) {
  __shared__ float  As[64 * 64];
  __shared__ __bf16 Bs[64 * 64];
  int tid = threadIdx.x;
  int w = tid >> 6, l = tid & 63;
  int l15 = l & 15, l7 = l & 7, g2 = l >> 4;
  int row0 = blockIdx.x * 64;
  int kbase = blockIdx.y * 4096;

  int a_row = w * 4 + (l >> 4);   // + c*16  (stage row)
  int b_col = w * 8 + (l >> 3);   // + c*32  (stage col)
  int m_row = w * 16 + l15;       // compute: A row within tile

  int phase = ((blockIdx.x + (blockIdx.x >> 3) + blockIdx.y) & 3) << 4;

  f32x4 acc0 = {0,0,0,0}, acc1 = {0,0,0,0}, acc2 = {0,0,0,0}, acc3 = {0,0,0,0};

  for (int it = 0; it < 64; ++it) {
    int ks = (it + phase) & 63;
    int kk = kbase + ks * 64;
#pragma unroll
    for (int c = 0; c < 4; ++c) {
      int r = c * 16 + a_row;
      const float* gp = x + (size_t)(row0 + r) * K_DIM + kk + ((l15 ^ (r & 15)) << 2);
      gload_lds16(gp, &As[c * 1024 + w * 256]);
    }
#pragma unroll
    for (int c = 0; c < 2; ++c) {
      int col = c * 32 + b_col;
      const __bf16* gp = WT + (size_t)col * K_DIM + kk + ((l7 ^ (col & 7)) << 3);
      gload_lds16(gp, &Bs[c * 2048 + w * 512]);
    }
    __syncthreads();
#pragma unroll
    for (int s = 0; s < 2; ++s) {
      int c0 = s * 8 + g2 * 2;
      f32x4 a0 = *(const f32x4*)&As[m_row * 64 + (((c0    ) ^ l15) << 2)];
      f32x4 a1 = *(const f32x4*)&As[m_row * 64 + (((c0 + 1) ^ l15) << 2)];
      bf16x8 af;
      af[0] = (__bf16)a0[0]; af[1] = (__bf16)a0[1]; af[2] = (__bf16)a0[2]; af[3] = (__bf16)a0[3];
      af[4] = (__bf16)a1[0]; af[5] = (__bf16)a1[1]; af[6] = (__bf16)a1[2]; af[7] = (__bf16)a1[3];
      int cb = (s * 4 + g2) ^ l7;   // swizzled B chunk
      bf16x8 b0 = *(const bf16x8*)&Bs[(     l15) * 64 + (cb << 3)];
      bf16x8 b1 = *(const bf16x8*)&Bs[(16 + l15) * 64 + (cb << 3)];
      bf16x8 b2 = *(const bf16x8*)&Bs[(32 + l15) * 64 + (cb << 3)];
      bf16x8 b3 = *(const bf16x8*)&Bs[(48 + l15) * 64 + (cb << 3)];
      acc0 = __builtin_amdgcn_mfma_f32_16x16x32_bf16(af, b0, acc0, 0, 0, 0);
      acc1 = __builtin_amdgcn_mfma_f32_16x16x32_bf16(af, b1, acc1, 0, 0, 0);
      acc2 = __builtin_amdgcn_mfma_f32_16x16x32_bf16(af, b2, acc2, 0, 0, 0);
      acc3 = __builtin_amdgcn_mfma_f32_16x16x32_bf16(af, b3, acc3, 0, 0, 0);
    }
    __syncthreads();
  }

  // C layout: col = lane&15, row = (lane>>4)*4 + reg; scale by dinv[row] = rsqrt(cnt+1) here
  int crow = row0 + w * 16 + g2 * 4;
#pragma unroll
  for (int j = 0; j < 4; ++j) {
    float dv = rsqrtf((float)(cnt[crow + j] + 1));
    size_t rb = (size_t)(crow + j) * H1_PAD + l15;
    atomicAdd(&xw[rb],      acc0[j] * dv);
    atomicAdd(&xw[rb + 16], acc1[j] * dv);
    atomicAdd(&xw[rb + 32], acc2[j] * dv);
    atomicAdd(&xw[rb + 48], acc3[j] * dv);
  }
}

// ---- layer-1 aggregation (xw rows pre-scaled by dinv[src]) FUSED with layer-2 transform ----
__global__ __launch_bounds__(256) void k_agg1(const float* __restrict__ xw,
                                              const int* __restrict__ cnt,
                                              const int* __restrict__ bucket,
                                              const float* __restrict__ b1,
                                              const float* __restrict__ W2,
                                              float* __restrict__ xw2s) {
  int tid = threadIdx.x;
  int nid = blockIdx.x * 4 + (tid >> 6);
  int j = tid & 63;
  float acc = xw[(size_t)nid * H1_PAD + j];  // self term (pre-scaled)
  int cn0 = cnt[nid];
  int cn = cn0 > CAP ? CAP : cn0;
  const int* bp = bucket + (size_t)nid * CAP;
  int p = 0;
  for (; p + 3 < cn; p += 4) {
    i32x4 s4 = *(const i32x4*)&bp[p];
    acc += xw[(size_t)s4[0] * H1_PAD + j];
    acc += xw[(size_t)s4[1] * H1_PAD + j];
    acc += xw[(size_t)s4[2] * H1_PAD + j];
    acc += xw[(size_t)s4[3] * H1_PAD + j];
  }
  for (; p < cn; ++p) acc += xw[(size_t)bp[p] * H1_PAD + j];

  float dv = rsqrtf((float)(cn0 + 1));
  float bj = (j < H1_DIM) ? b1[j] : 0.f;
  float h = tanhf(dv * acc + bj);
  float w0 = (j < H1_DIM) ? W2[j * 2]     : 0.f;
  float w1 = (j < H1_DIM) ? W2[j * 2 + 1] : 0.f;
  float a0 = h * w0, a1 = h * w1;
#pragma unroll
  for (int off = 32; off >= 1; off >>= 1) {
    a0 += __shfl_xor(a0, off);
    a1 += __shfl_xor(a1, off);
  }
  if (j == 0) {
    xw2s[nid * 2]     = a0 * dv;
    xw2s[nid * 2 + 1] = a1 * dv;
  }
}

// ---------------- layer-2 aggregation + tanh + classifier ----------------
__global__ __launch_bounds__(256) void k_final(const float* __restrict__ xw2s,
                                               const int* __restrict__ cnt,
                                               const int* __restrict__ bucket,
                                               const float* __restrict__ b2,
                                               const float* __restrict__ Wc,
                                               const float* __restrict__ bc,
                                               float* __restrict__ dout) {
  int tid = threadIdx.x;
  int g = tid >> 4, r = tid & 15;
  int nid = blockIdx.x * 16 + g;
  int cn0 = cnt[nid];
  int cn = cn0 > CAP ? CAP : cn0;
  const int* bp = bucket + (size_t)nid * CAP;
  float a0 = 0.f, a1 = 0.f;
  for (int p = r; p < cn; p += 16) {
    int sc = bp[p];
    a0 += xw2s[sc * 2];
    a1 += xw2s[sc * 2 + 1];
  }
#pragma unroll
  for (int off = 8; off >= 1; off >>= 1) {
    a0 += __shfl_xor(a0, off, 16);
    a1 += __shfl_xor(a1, off, 16);
  }
  if (r == 0) {
    a0 += xw2s[nid * 2];
    a1 += xw2s[nid * 2 + 1];
    float dv = rsqrtf((float)(cn0 + 1));
    float h0  = tanhf(dv * a0 + b2[0]);
    float h1v = tanhf(dv * a1 + b2[1]);
#pragma unroll
    for (int j = 0; j < 7; ++j)
      dout[nid * 7 + j] = h0 * Wc[j] + h1v * Wc[7 + j] + bc[j];
    dout[OUT_OFF + nid * 2]     = h0;
    dout[OUT_OFF + nid * 2 + 1] = h1v;
  }
}

extern "C" void kernel_launch(void* const* d_in, const int* in_sizes, int n_in,
                              void* d_out, int out_size, void* d_ws, size_t ws_size,
                              hipStream_t stream) {
  const float* x  = (const float*)d_in[0];
  const int*   ei = (const int*)d_in[1];
  const float* W1 = (const float*)d_in[2];
  const float* b1 = (const float*)d_in[3];
  const float* W2 = (const float*)d_in[4];
  const float* b2 = (const float*)d_in[5];
  const float* Wc = (const float*)d_in[6];
  const float* bc = (const float*)d_in[7];
  float* dout = (float*)d_out;
  const int E = in_sizes[1] / 2;
  const int* esrc = ei;
  const int* edst = ei + E;

  char* ws = (char*)d_ws;
  float*  xw      = (float*)(ws + 0x0000000);   // 4 MiB  [16384][64]
  __bf16* WT      = (__bf16*)(ws + 0x0400000);  // 2 MiB  [64][16384]
  int*    cnt     = (int*)(ws + 0x0600000);     // 64 KiB
  int*    bucket  = (int*)(ws + 0x0620000);     // 10 MiB [16384][160]
  float*  xw2s    = (float*)(ws + 0x1100000);   // 128 KiB

  k_init<<<1344, 256, 0, stream>>>(W1, WT, xw, cnt);
  k_fill<<<(E + 255) / 256, 256, 0, stream>>>(esrc, edst, E, cnt, bucket);
  k_gemm1<<<dim3(256, 4), 256, 0, stream>>>(x, WT, cnt, xw);
  k_agg1<<<N_NODES / 4, 256, 0, stream>>>(xw, cnt, bucket, b1, W2, xw2s);
  k_final<<<N_NODES / 16, 256, 0, stream>>>(xw2s, cnt, bucket, b2, Wc, bc, dout);
}